// Round 7
// baseline (742.730 us; speedup 1.0000x reference)
//
#include <hip/hip_runtime.h>
#include <hip/hip_bf16.h>

typedef __attribute__((ext_vector_type(8))) __bf16 bf16x8;
typedef __attribute__((ext_vector_type(4))) float floatx4;
typedef unsigned short ushort_t;
typedef unsigned int uint_t;

#define N_NODES 100000
#define NNZ_E   3200000
#define N_IDX   50000
#define NB_BKT  196        // buckets of 512 rows: row >> 9
#define PTILE   8192
#define PBLOCKS 391        // ceil(NNZ_E / PTILE)

__device__ __forceinline__ float bf2f(uint_t u16) {
  union { float f; uint_t i; } v; v.i = u16 << 16; return v.f;
}
__device__ __forceinline__ unsigned short f2bf(float f) {
  union { float f; uint_t i; } v; v.f = f;
  uint_t x = v.i;
  return (unsigned short)((x + 0x7FFFu + ((x >> 16) & 1u)) >> 16);
}

// ---------------- CSR construction (temporally-dense two-level partition) ---------

__global__ __launch_bounds__(256) void k_bhist(const int* __restrict__ rows,
                                               int* __restrict__ bcnt) {
  __shared__ int h[NB_BKT];
  for (int i = threadIdx.x; i < NB_BKT; i += 256) h[i] = 0;
  __syncthreads();
  int base = blockIdx.x * PTILE;
  for (int i = threadIdx.x; i < PTILE; i += 256) {
    int e = base + i;
    if (e < NNZ_E) atomicAdd(&h[rows[e] >> 9], 1);
  }
  __syncthreads();
  for (int i = threadIdx.x; i < NB_BKT; i += 256)
    if (h[i]) atomicAdd(&bcnt[i], h[i]);
}

__global__ void k_bscan(const int* __restrict__ bcnt, int* __restrict__ bbase,
                        int* __restrict__ bcur) {
  __shared__ int ts[256];
  int t = threadIdx.x;
  int v = (t < NB_BKT) ? bcnt[t] : 0;
  ts[t] = v;
  __syncthreads();
  for (int off = 1; off < 256; off <<= 1) {
    int x = ts[t];
    int a = (t >= off) ? ts[t - off] : 0;
    __syncthreads();
    ts[t] = x + a;
    __syncthreads();
  }
  if (t < NB_BKT) {
    int b = (t == 0) ? 0 : ts[t - 1];
    bbase[t] = b;
    bcur[t] = b;
  }
}

// partition into 196 coarse buckets; packed edge: col | (row&511)<<17, val
__global__ __launch_bounds__(256) void k_part(const int* __restrict__ rows,
                                              const int* __restrict__ cols,
                                              const float* __restrict__ vals,
                                              int* __restrict__ bcur,
                                              int2* __restrict__ tmp) {
  __shared__ int h[NB_BKT];
  for (int i = threadIdx.x; i < NB_BKT; i += 256) h[i] = 0;
  __syncthreads();
  int base = blockIdx.x * PTILE;
  for (int i = threadIdx.x; i < PTILE; i += 256) {
    int e = base + i;
    if (e < NNZ_E) atomicAdd(&h[rows[e] >> 9], 1);
  }
  __syncthreads();
  for (int i = threadIdx.x; i < NB_BKT; i += 256) {
    int c = h[i];
    h[i] = c ? atomicAdd(&bcur[i], c) : 0;
  }
  __syncthreads();
  for (int i = threadIdx.x; i < PTILE; i += 256) {
    int e = base + i;
    if (e < NNZ_E) {
      int rr = rows[e];
      int p = atomicAdd(&h[rr >> 9], 1);
      int2 o;
      o.x = cols[e] | ((rr & 511) << 17);
      o.y = __float_as_int(vals[e]);
      tmp[p] = o;
    }
  }
}

// one block per bucket: 512-row LDS counting sort -> final edges[] (col<<8) + rowptr
__global__ __launch_bounds__(512) void k_sort(const int* __restrict__ bbase,
                                              const int2* __restrict__ tmp,
                                              int2* __restrict__ edges,
                                              int* __restrict__ rowptr) {
  __shared__ int cnt[512];
  __shared__ int ts[512];
  int b = blockIdx.x, t = threadIdx.x;
  int s = bbase[b];
  int epos = (b == NB_BKT - 1) ? NNZ_E : bbase[b + 1];
  cnt[t] = 0;
  __syncthreads();
  for (int i = s + t; i < epos; i += 512)
    atomicAdd(&cnt[(tmp[i].x >> 17) & 511], 1);
  __syncthreads();
  ts[t] = cnt[t];
  __syncthreads();
  for (int off = 1; off < 512; off <<= 1) {
    int x = ts[t];
    int a = (t >= off) ? ts[t - off] : 0;
    __syncthreads();
    ts[t] = x + a;
    __syncthreads();
  }
  int pre = (t == 0) ? 0 : ts[t - 1];
  int grow = b * 512 + t;
  if (grow < N_NODES) rowptr[grow] = s + pre;
  cnt[t] = s + pre;            // per-row write cursor
  __syncthreads();
  for (int i = s + t; i < epos; i += 512) {
    int2 p = tmp[i];
    int rl = (p.x >> 17) & 511;
    int pos = atomicAdd(&cnt[rl], 1);
    int2 o;
    o.x = (p.x & 0x1FFFF) << 8;   // byte offset at 256B row stride
    o.y = p.y;
    edges[pos] = o;
  }
  if (b == 0 && t == 0) rowptr[N_NODES] = NNZ_E;
}

// ---------------- fp32 -> bf16 convert ----------------

__global__ void k_cvt(const float4* __restrict__ x, ushort4* __restrict__ xb) {
  int i = blockIdx.x * blockDim.x + threadIdx.x;
  if (i < N_NODES * 128 / 4) {
    float4 v = x[i];
    ushort4 o;
    o.x = f2bf(v.x); o.y = f2bf(v.y); o.z = f2bf(v.z); o.w = f2bf(v.w);
    xb[i] = o;
  }
}

// ---------------- weight packing (B-fragment layout) ----------------

__global__ void k_prepW1(const float* __restrict__ W, ushort_t* __restrict__ Wp) {
  int kp = blockIdx.x;    // chunk*128 + f, 0..383
  int n  = threadIdx.x;   // 0..255
  int ch = kp >> 7;
  int f  = kp & 127;
  float v;
  if (ch == 0)      v = W[(f*3+0)*256+n] - W[(f*3+2)*256+n];
  else if (ch == 1) v = W[(f*3+1)*256+n];
  else              v = 2.0f * W[(f*3+2)*256+n];
  int kb = kp >> 5, kr = kp & 31;
  int lane = ((kr >> 3) << 4) | (n & 15);
  Wp[(((size_t)kb * 16 + (n >> 4)) * 64 + lane) * 8 + (kr & 7)] = f2bf(v);
}

__global__ void k_prepW2(const float* __restrict__ W, ushort_t* __restrict__ Wp) {
  int f = blockIdx.x;     // 0..255
  int c = threadIdx.x;    // 0..191
  int g = c >> 6, n = c & 63;
  float v;
  if (g == 0)      v = W[(f*3+0)*64+n] - W[(f*3+2)*64+n];
  else if (g == 1) v = W[(f*3+1)*64+n];
  else             v = 2.0f * W[(f*3+2)*64+n];
  int kb = f >> 5, kr = f & 31;
  int nb = c >> 4;
  int lane = ((kr >> 3) << 4) | (c & 15);
  Wp[(((size_t)kb * 12 + nb) * 64 + lane) * 8 + (kr & 7)] = f2bf(v);
}

// ---------------- SpMM, 128 features (layer 1) ----------------
// 4 rows/block (1 wave each), 16-deep edge unroll; gathers use 32-bit
// byte-offset (edges store col<<8) -> single OR + saddr load per gather.

__global__ __launch_bounds__(256) void k_spmm128(
    const int* __restrict__ rowptr, const int2* __restrict__ edges,
    const ushort_t* __restrict__ in, ushort_t* __restrict__ out) {
  int r = blockIdx.x * 4 + (threadIdx.x >> 6);
  int f = threadIdx.x & 63;
  uint_t fo = (uint_t)f << 2;
  const char* inb = (const char*)in;
  int e0 = rowptr[r], e1 = rowptr[r + 1];
  float a0 = 0.f, a1 = 0.f;
  int e = e0;
  for (; e + 16 <= e1; e += 16) {
    int2 E[16];
#pragma unroll
    for (int j = 0; j < 16; ++j) E[j] = edges[e + j];
    uint_t q[16];
#pragma unroll
    for (int j = 0; j < 16; ++j)
      q[j] = *(const uint_t*)(inb + (((uint_t)E[j].x) | fo));
#pragma unroll
    for (int j = 0; j < 16; ++j) {
      float v = __int_as_float(E[j].y);
      a0 = fmaf(v, bf2f(q[j] & 0xFFFFu), a0);
      a1 = fmaf(v, bf2f(q[j] >> 16), a1);
    }
  }
  for (; e + 4 <= e1; e += 4) {
    int2 E[4];
#pragma unroll
    for (int j = 0; j < 4; ++j) E[j] = edges[e + j];
#pragma unroll
    for (int j = 0; j < 4; ++j) {
      uint_t q = *(const uint_t*)(inb + (((uint_t)E[j].x) | fo));
      float v = __int_as_float(E[j].y);
      a0 = fmaf(v, bf2f(q & 0xFFFFu), a0);
      a1 = fmaf(v, bf2f(q >> 16), a1);
    }
  }
  for (; e < e1; ++e) {
    int2 E = edges[e];
    uint_t q = *(const uint_t*)(inb + (((uint_t)E.x) | fo));
    float v = __int_as_float(E.y);
    a0 = fmaf(v, bf2f(q & 0xFFFFu), a0);
    a1 = fmaf(v, bf2f(q >> 16), a1);
  }
  uint_t o = ((uint_t)f2bf(a1) << 16) | (uint_t)f2bf(a0);
  *(uint_t*)(out + (size_t)r * 128 + 2 * f) = o;
}

// ---------------- SpMM, 64 features: u = p1 + L p2 ----------------
// wave halves take contiguous half-ranges, 8-deep unroll, shfl_xor(32) combine

__global__ __launch_bounds__(256) void k_spmm64_add(
    const int* __restrict__ rowptr, const int2* __restrict__ edges,
    const ushort_t* __restrict__ p2, const ushort_t* __restrict__ p1,
    ushort_t* __restrict__ u) {
  int r = blockIdx.x * 4 + (threadIdx.x >> 6);
  int lane = threadIdx.x & 63;
  int half = lane >> 5, f = lane & 31;
  uint_t fo = (uint_t)f << 2;
  const char* pb = (const char*)p2;
  int e0 = rowptr[r], e1 = rowptr[r + 1];
  int ne = e1 - e0;
  int hs = (ne + 1) >> 1;
  int e = e0 + half * hs;
  int send = half ? e1 : (e0 + hs);
  float a0 = 0.f, a1 = 0.f;
  for (; e + 8 <= send; e += 8) {
    int2 E[8];
#pragma unroll
    for (int j = 0; j < 8; ++j) E[j] = edges[e + j];
    uint_t q[8];
#pragma unroll
    for (int j = 0; j < 8; ++j)
      q[j] = *(const uint_t*)(pb + ((((uint_t)E[j].x) >> 1) | fo));
#pragma unroll
    for (int j = 0; j < 8; ++j) {
      float v = __int_as_float(E[j].y);
      a0 = fmaf(v, bf2f(q[j] & 0xFFFFu), a0);
      a1 = fmaf(v, bf2f(q[j] >> 16), a1);
    }
  }
  for (; e < send; ++e) {
    int2 E = edges[e];
    uint_t q = *(const uint_t*)(pb + ((((uint_t)E.x) >> 1) | fo));
    float v = __int_as_float(E.y);
    a0 = fmaf(v, bf2f(q & 0xFFFFu), a0);
    a1 = fmaf(v, bf2f(q >> 16), a1);
  }
  a0 += __shfl_xor(a0, 32);
  a1 += __shfl_xor(a1, 32);
  if (half == 0) {
    uint_t pp = *(const uint_t*)(p1 + (size_t)r * 64 + 2 * f);
    float b0 = a0 + bf2f(pp & 0xFFFFu);
    float b1 = a1 + bf2f(pp >> 16);
    uint_t o = ((uint_t)f2bf(b1) << 16) | (uint_t)f2bf(b0);
    *(uint_t*)(u + (size_t)r * 64 + 2 * f) = o;
  }
}

// ---------------- SpMM, 64 features over idx rows: out = p0[idx] + L u ----------------

__global__ __launch_bounds__(256) void k_spmm64_idx(
    const int* __restrict__ rowptr, const int2* __restrict__ edges,
    const ushort_t* __restrict__ u, const float* __restrict__ p0,
    const int* __restrict__ idx, float* __restrict__ out) {
  int o = blockIdx.x * 4 + (threadIdx.x >> 6);
  int r = idx[o];
  int lane = threadIdx.x & 63;
  int half = lane >> 5, f = lane & 31;
  uint_t fo = (uint_t)f << 2;
  const char* ub = (const char*)u;
  int e0 = rowptr[r], e1 = rowptr[r + 1];
  int ne = e1 - e0;
  int hs = (ne + 1) >> 1;
  int e = e0 + half * hs;
  int send = half ? e1 : (e0 + hs);
  float a0 = 0.f, a1 = 0.f;
  for (; e + 8 <= send; e += 8) {
    int2 E[8];
#pragma unroll
    for (int j = 0; j < 8; ++j) E[j] = edges[e + j];
    uint_t q[8];
#pragma unroll
    for (int j = 0; j < 8; ++j)
      q[j] = *(const uint_t*)(ub + ((((uint_t)E[j].x) >> 1) | fo));
#pragma unroll
    for (int j = 0; j < 8; ++j) {
      float v = __int_as_float(E[j].y);
      a0 = fmaf(v, bf2f(q[j] & 0xFFFFu), a0);
      a1 = fmaf(v, bf2f(q[j] >> 16), a1);
    }
  }
  for (; e < send; ++e) {
    int2 E = edges[e];
    uint_t q = *(const uint_t*)(ub + ((((uint_t)E.x) >> 1) | fo));
    float v = __int_as_float(E.y);
    a0 = fmaf(v, bf2f(q & 0xFFFFu), a0);
    a1 = fmaf(v, bf2f(q >> 16), a1);
  }
  a0 += __shfl_xor(a0, 32);
  a1 += __shfl_xor(a1, 32);
  if (half == 0) {
    float2 b = *(const float2*)(p0 + (size_t)r * 64 + 2 * f);
    float2 w; w.x = b.x + a0; w.y = b.y + a1;
    *(float2*)(out + (size_t)o * 64 + 2 * f) = w;
  }
}

// ---------------- GEMM1: h = relu([x|T1|U] @ Weff1 + b1), M=100k K=384 N=256 ----------
// one wave -> 16 rows x all 16 n-tiles (A read exactly once)

__global__ __launch_bounds__(256) void k_gemm1(
    const ushort_t* __restrict__ A0, const ushort_t* __restrict__ A1,
    const ushort_t* __restrict__ A2, const ushort_t* __restrict__ Bp,
    const float* __restrict__ bias, ushort_t* __restrict__ h) {
  int wid = (blockIdx.x * 256 + threadIdx.x) >> 6;   // m-tile, 0..6249
  if (wid >= 6250) return;
  int lane = threadIdx.x & 63;
  int mr = wid * 16 + (lane & 15);
  int ko = (lane >> 4) << 3;
  floatx4 acc[16] = {};
#pragma unroll
  for (int c = 0; c < 3; ++c) {
    const ushort_t* Ab = (c == 0 ? A0 : c == 1 ? A1 : A2) + (size_t)mr * 128 + ko;
#pragma unroll
    for (int kb = 0; kb < 4; ++kb) {
      bf16x8 a = *(const bf16x8*)(Ab + kb * 32);
      int kbg = c * 4 + kb;
      const ushort_t* Bb = Bp + (((size_t)kbg * 16 * 64) + lane) * 8;
#pragma unroll
      for (int nt = 0; nt < 16; ++nt) {
        bf16x8 b = *(const bf16x8*)(Bb + (size_t)nt * 64 * 8);
        acc[nt] = __builtin_amdgcn_mfma_f32_16x16x32_bf16(a, b, acc[nt], 0, 0, 0);
      }
    }
  }
  int c16 = lane & 15;
  int r0 = wid * 16 + ((lane >> 4) << 2);
#pragma unroll
  for (int nt = 0; nt < 16; ++nt) {
    int col = nt * 16 + c16;
    float bv = bias[col];
#pragma unroll
    for (int rg = 0; rg < 4; ++rg) {
      float v = acc[nt][rg] + bv;
      v = v > 0.f ? v : 0.f;
      h[(size_t)(r0 + rg) * 256 + col] = f2bf(v);
    }
  }
}

// ---------------- GEMM2: [p0|p1|p2] = h @ Weff2 (+b2 on p0), M=100k K=256 N=192 -------

__global__ __launch_bounds__(256) void k_gemm2(
    const ushort_t* __restrict__ A, const ushort_t* __restrict__ Bp,
    const float* __restrict__ bias, float* __restrict__ p0,
    ushort_t* __restrict__ p1, ushort_t* __restrict__ p2) {
  int wid = (blockIdx.x * 256 + threadIdx.x) >> 6;
  if (wid >= 18750) return;
  int lane = threadIdx.x & 63;
  int mt = wid / 3, ng = wid - mt * 3;   // ng: 0=p0, 1=p1, 2=p2
  int mr = mt * 16 + (lane & 15);
  int ko = (lane >> 4) << 3;
  floatx4 acc[4] = {};
  const ushort_t* Ab = A + (size_t)mr * 256 + ko;
#pragma unroll
  for (int kb = 0; kb < 8; ++kb) {
    bf16x8 a = *(const bf16x8*)(Ab + kb * 32);
    const ushort_t* Bb = Bp + (((size_t)(kb * 12 + ng * 4)) * 64 + lane) * 8;
#pragma unroll
    for (int nt = 0; nt < 4; ++nt) {
      bf16x8 b = *(const bf16x8*)(Bb + (size_t)nt * 64 * 8);
      acc[nt] = __builtin_amdgcn_mfma_f32_16x16x32_bf16(a, b, acc[nt], 0, 0, 0);
    }
  }
  int c16 = lane & 15;
  int r0 = mt * 16 + ((lane >> 4) << 2);
  if (ng == 0) {
#pragma unroll
    for (int nt = 0; nt < 4; ++nt) {
      float bv = bias[nt * 16 + c16];
#pragma unroll
      for (int rg = 0; rg < 4; ++rg)
        p0[(size_t)(r0 + rg) * 64 + nt * 16 + c16] = acc[nt][rg] + bv;
    }
  } else {
    ushort_t* dst = (ng == 1) ? p1 : p2;
#pragma unroll
    for (int nt = 0; nt < 4; ++nt)
#pragma unroll
      for (int rg = 0; rg < 4; ++rg)
        dst[(size_t)(r0 + rg) * 64 + nt * 16 + c16] = f2bf(acc[nt][rg]);
  }
}

// ---------------- launch ----------------

extern "C" void kernel_launch(void* const* d_in, const int* in_sizes, int n_in,
                              void* d_out, int out_size, void* d_ws, size_t ws_size,
                              hipStream_t stream) {
  const float* x    = (const float*)d_in[0];
  const float* vals = (const float*)d_in[1];
  const float* W1   = (const float*)d_in[2];
  const float* b1   = (const float*)d_in[3];
  const float* W2   = (const float*)d_in[4];
  const float* b2   = (const float*)d_in[5];
  const int*   rows = (const int*)d_in[6];
  const int*   cols = (const int*)d_in[7];
  const int*   idx  = (const int*)d_in[8];
  float* out = (float*)d_out;

  char* w = (char*)d_ws;
  size_t off = 0;
  auto take = [&](size_t b) -> char* {
    char* p = w + off;
    off += (b + 255) & ~(size_t)255;
    return p;
  };
  int*      bcnt    = (int*)take((size_t)NB_BKT * 4);
  int*      bbase   = (int*)take((size_t)NB_BKT * 4);
  int*      bcur    = (int*)take((size_t)NB_BKT * 4);
  int*      rowptr  = (int*)take((size_t)(N_NODES + 1) * 4);
  int2*     tmp     = (int2*)take((size_t)NNZ_E * 8);
  int2*     edges   = (int2*)take((size_t)NNZ_E * 8);
  ushort_t* xb      = (ushort_t*)take((size_t)N_NODES * 128 * 2);  // later: p0 (fp32 100k x 64)
  ushort_t* T1a     = (ushort_t*)take((size_t)N_NODES * 128 * 2);  // later: p1 | p2
  ushort_t* U1      = (ushort_t*)take((size_t)N_NODES * 128 * 2);  // later: u
  ushort_t* h       = (ushort_t*)take((size_t)N_NODES * 256 * 2);
  ushort_t* W1p     = (ushort_t*)take((size_t)384 * 256 * 2);
  ushort_t* W2p     = (ushort_t*)take((size_t)256 * 192 * 2);

  // overlays (dead after GEMM1 consumes xb/T1a/U1)
  float*    p0 = (float*)xb;                                   // 25.6 MB, exact fit
  ushort_t* p1 = T1a;                                          // 12.8 MB
  ushort_t* p2 = T1a + (size_t)N_NODES * 64;                   // 12.8 MB
  ushort_t* u  = U1;                                           // 12.8 MB

  // CSR build (graph shared by both layers)
  hipMemsetAsync(bcnt, 0, (size_t)NB_BKT * 4, stream);
  k_bhist<<<PBLOCKS, 256, 0, stream>>>(rows, bcnt);
  k_bscan<<<1, 256, 0, stream>>>(bcnt, bbase, bcur);
  k_part<<<PBLOCKS, 256, 0, stream>>>(rows, cols, vals, bcur, tmp);
  k_sort<<<NB_BKT, 512, 0, stream>>>(bbase, tmp, edges, rowptr);

  // prep
  k_cvt<<<(N_NODES * 128 / 4 + 255) / 256, 256, 0, stream>>>((const float4*)x, (ushort4*)xb);
  k_prepW1<<<384, 256, 0, stream>>>(W1, W1p);
  k_prepW2<<<256, 192, 0, stream>>>(W2, W2p);

  // layer 1: T1 = L x ; U = L T1 ; h = relu([x|T1|U] @ Weff1 + b1)
  k_spmm128<<<N_NODES / 4, 256, 0, stream>>>(rowptr, edges, xb, T1a);
  k_spmm128<<<N_NODES / 4, 256, 0, stream>>>(rowptr, edges, T1a, U1);
  k_gemm1<<<1563, 256, 0, stream>>>(xb, T1a, U1, W1p, b1, h);

  // layer 2 (L pushed past the GEMM): [p0|p1|p2] = h @ Weff2 ; u = p1 + L p2 ;
  // out = p0[idx] + (L u)[idx]
  k_gemm2<<<4688, 256, 0, stream>>>(h, W2p, b2, p0, p1, p2);
  k_spmm64_add<<<N_NODES / 4, 256, 0, stream>>>(rowptr, edges, p2, p1, u);
  k_spmm64_idx<<<N_IDX / 4, 256, 0, stream>>>(rowptr, edges, u, p0, idx, out);
}

// Round 8
// 691.764 us; speedup vs baseline: 1.0737x; 1.0737x over previous
//
#include <hip/hip_runtime.h>
#include <hip/hip_bf16.h>

typedef __attribute__((ext_vector_type(8))) __bf16 bf16x8;
typedef __attribute__((ext_vector_type(4))) float floatx4;
typedef unsigned short ushort_t;
typedef unsigned int uint_t;

#define N_NODES 100000
#define NNZ_E   3200000
#define N_IDX   50000
#define NB_BKT  196        // buckets of 512 rows: row >> 9
#define PTILE   8192
#define PBLOCKS 391        // ceil(NNZ_E / PTILE)

__device__ __forceinline__ float bf2f(uint_t u16) {
  union { float f; uint_t i; } v; v.i = u16 << 16; return v.f;
}
__device__ __forceinline__ unsigned short f2bf(float f) {
  union { float f; uint_t i; } v; v.f = f;
  uint_t x = v.i;
  return (unsigned short)((x + 0x7FFFu + ((x >> 16) & 1u)) >> 16);
}

// ---------------- CSR construction (temporally-dense two-level partition) ---------

__global__ __launch_bounds__(256) void k_bhist(const int* __restrict__ rows,
                                               int* __restrict__ bcnt) {
  __shared__ int h[NB_BKT];
  for (int i = threadIdx.x; i < NB_BKT; i += 256) h[i] = 0;
  __syncthreads();
  int base = blockIdx.x * PTILE;
  for (int i = threadIdx.x; i < PTILE; i += 256) {
    int e = base + i;
    if (e < NNZ_E) atomicAdd(&h[rows[e] >> 9], 1);
  }
  __syncthreads();
  for (int i = threadIdx.x; i < NB_BKT; i += 256)
    if (h[i]) atomicAdd(&bcnt[i], h[i]);
}

__global__ void k_bscan(const int* __restrict__ bcnt, int* __restrict__ bbase,
                        int* __restrict__ bcur) {
  __shared__ int ts[256];
  int t = threadIdx.x;
  int v = (t < NB_BKT) ? bcnt[t] : 0;
  ts[t] = v;
  __syncthreads();
  for (int off = 1; off < 256; off <<= 1) {
    int x = ts[t];
    int a = (t >= off) ? ts[t - off] : 0;
    __syncthreads();
    ts[t] = x + a;
    __syncthreads();
  }
  if (t < NB_BKT) {
    int b = (t == 0) ? 0 : ts[t - 1];
    bbase[t] = b;
    bcur[t] = b;
  }
}

// partition into 196 coarse buckets; packed edge: col | (row&511)<<17, val
__global__ __launch_bounds__(256) void k_part(const int* __restrict__ rows,
                                              const int* __restrict__ cols,
                                              const float* __restrict__ vals,
                                              int* __restrict__ bcur,
                                              int2* __restrict__ tmp) {
  __shared__ int h[NB_BKT];
  for (int i = threadIdx.x; i < NB_BKT; i += 256) h[i] = 0;
  __syncthreads();
  int base = blockIdx.x * PTILE;
  for (int i = threadIdx.x; i < PTILE; i += 256) {
    int e = base + i;
    if (e < NNZ_E) atomicAdd(&h[rows[e] >> 9], 1);
  }
  __syncthreads();
  for (int i = threadIdx.x; i < NB_BKT; i += 256) {
    int c = h[i];
    h[i] = c ? atomicAdd(&bcur[i], c) : 0;
  }
  __syncthreads();
  for (int i = threadIdx.x; i < PTILE; i += 256) {
    int e = base + i;
    if (e < NNZ_E) {
      int rr = rows[e];
      int p = atomicAdd(&h[rr >> 9], 1);
      int2 o;
      o.x = cols[e] | ((rr & 511) << 17);
      o.y = __float_as_int(vals[e]);
      tmp[p] = o;
    }
  }
}

// one block per bucket: 512-row LDS counting sort -> final edges[] (col<<8) + rowptr
__global__ __launch_bounds__(512) void k_sort(const int* __restrict__ bbase,
                                              const int2* __restrict__ tmp,
                                              int2* __restrict__ edges,
                                              int* __restrict__ rowptr) {
  __shared__ int cnt[512];
  __shared__ int ts[512];
  int b = blockIdx.x, t = threadIdx.x;
  int s = bbase[b];
  int epos = (b == NB_BKT - 1) ? NNZ_E : bbase[b + 1];
  cnt[t] = 0;
  __syncthreads();
  for (int i = s + t; i < epos; i += 512)
    atomicAdd(&cnt[(tmp[i].x >> 17) & 511], 1);
  __syncthreads();
  ts[t] = cnt[t];
  __syncthreads();
  for (int off = 1; off < 512; off <<= 1) {
    int x = ts[t];
    int a = (t >= off) ? ts[t - off] : 0;
    __syncthreads();
    ts[t] = x + a;
    __syncthreads();
  }
  int pre = (t == 0) ? 0 : ts[t - 1];
  int grow = b * 512 + t;
  if (grow < N_NODES) rowptr[grow] = s + pre;
  cnt[t] = s + pre;            // per-row write cursor
  __syncthreads();
  for (int i = s + t; i < epos; i += 512) {
    int2 p = tmp[i];
    int rl = (p.x >> 17) & 511;
    int pos = atomicAdd(&cnt[rl], 1);
    int2 o;
    o.x = (p.x & 0x1FFFF) << 8;   // byte offset at 256B row stride
    o.y = p.y;
    edges[pos] = o;
  }
  if (b == 0 && t == 0) rowptr[N_NODES] = NNZ_E;
}

// ---------------- fp32 -> bf16 convert ----------------

__global__ void k_cvt(const float4* __restrict__ x, ushort4* __restrict__ xb) {
  int i = blockIdx.x * blockDim.x + threadIdx.x;
  if (i < N_NODES * 128 / 4) {
    float4 v = x[i];
    ushort4 o;
    o.x = f2bf(v.x); o.y = f2bf(v.y); o.z = f2bf(v.z); o.w = f2bf(v.w);
    xb[i] = o;
  }
}

// ---------------- weight packing (B-fragment layout) ----------------

__global__ void k_prepW1(const float* __restrict__ W, ushort_t* __restrict__ Wp) {
  int kp = blockIdx.x;    // chunk*128 + f, 0..383
  int n  = threadIdx.x;   // 0..255
  int ch = kp >> 7;
  int f  = kp & 127;
  float v;
  if (ch == 0)      v = W[(f*3+0)*256+n] - W[(f*3+2)*256+n];
  else if (ch == 1) v = W[(f*3+1)*256+n];
  else              v = 2.0f * W[(f*3+2)*256+n];
  int kb = kp >> 5, kr = kp & 31;
  int lane = ((kr >> 3) << 4) | (n & 15);
  Wp[(((size_t)kb * 16 + (n >> 4)) * 64 + lane) * 8 + (kr & 7)] = f2bf(v);
}

__global__ void k_prepW2(const float* __restrict__ W, ushort_t* __restrict__ Wp) {
  int f = blockIdx.x;     // 0..255
  int c = threadIdx.x;    // 0..191
  int g = c >> 6, n = c & 63;
  float v;
  if (g == 0)      v = W[(f*3+0)*64+n] - W[(f*3+2)*64+n];
  else if (g == 1) v = W[(f*3+1)*64+n];
  else             v = 2.0f * W[(f*3+2)*64+n];
  int kb = f >> 5, kr = f & 31;
  int nb = c >> 4;
  int lane = ((kr >> 3) << 4) | (c & 15);
  Wp[(((size_t)kb * 12 + nb) * 64 + lane) * 8 + (kr & 7)] = f2bf(v);
}

// ---------------- SpMM, 128 features (layer 1) ----------------
// 4 rows/block (1 wave each), 16-deep edge unroll; gathers use 32-bit
// byte-offset (edges store col<<8) -> single OR + saddr load per gather.

__global__ __launch_bounds__(256) void k_spmm128(
    const int* __restrict__ rowptr, const int2* __restrict__ edges,
    const ushort_t* __restrict__ in, ushort_t* __restrict__ out) {
  int r = blockIdx.x * 4 + (threadIdx.x >> 6);
  int f = threadIdx.x & 63;
  uint_t fo = (uint_t)f << 2;
  const char* inb = (const char*)in;
  int e0 = rowptr[r], e1 = rowptr[r + 1];
  float a0 = 0.f, a1 = 0.f;
  int e = e0;
  for (; e + 16 <= e1; e += 16) {
    int2 E[16];
#pragma unroll
    for (int j = 0; j < 16; ++j) E[j] = edges[e + j];
    uint_t q[16];
#pragma unroll
    for (int j = 0; j < 16; ++j)
      q[j] = *(const uint_t*)(inb + (((uint_t)E[j].x) | fo));
#pragma unroll
    for (int j = 0; j < 16; ++j) {
      float v = __int_as_float(E[j].y);
      a0 = fmaf(v, bf2f(q[j] & 0xFFFFu), a0);
      a1 = fmaf(v, bf2f(q[j] >> 16), a1);
    }
  }
  for (; e + 4 <= e1; e += 4) {
    int2 E[4];
#pragma unroll
    for (int j = 0; j < 4; ++j) E[j] = edges[e + j];
#pragma unroll
    for (int j = 0; j < 4; ++j) {
      uint_t q = *(const uint_t*)(inb + (((uint_t)E[j].x) | fo));
      float v = __int_as_float(E[j].y);
      a0 = fmaf(v, bf2f(q & 0xFFFFu), a0);
      a1 = fmaf(v, bf2f(q >> 16), a1);
    }
  }
  for (; e < e1; ++e) {
    int2 E = edges[e];
    uint_t q = *(const uint_t*)(inb + (((uint_t)E.x) | fo));
    float v = __int_as_float(E.y);
    a0 = fmaf(v, bf2f(q & 0xFFFFu), a0);
    a1 = fmaf(v, bf2f(q >> 16), a1);
  }
  uint_t o = ((uint_t)f2bf(a1) << 16) | (uint_t)f2bf(a0);
  *(uint_t*)(out + (size_t)r * 128 + 2 * f) = o;
}

// ---------------- SpMM, 64 features: u = p1 + L p2 ----------------
// wave halves take contiguous half-ranges, 8-deep unroll, shfl_xor(32) combine

__global__ __launch_bounds__(256) void k_spmm64_add(
    const int* __restrict__ rowptr, const int2* __restrict__ edges,
    const ushort_t* __restrict__ p2, const ushort_t* __restrict__ p1,
    ushort_t* __restrict__ u) {
  int r = blockIdx.x * 4 + (threadIdx.x >> 6);
  int lane = threadIdx.x & 63;
  int half = lane >> 5, f = lane & 31;
  uint_t fo = (uint_t)f << 2;
  const char* pb = (const char*)p2;
  int e0 = rowptr[r], e1 = rowptr[r + 1];
  int ne = e1 - e0;
  int hs = (ne + 1) >> 1;
  int e = e0 + half * hs;
  int send = half ? e1 : (e0 + hs);
  float a0 = 0.f, a1 = 0.f;
  for (; e + 8 <= send; e += 8) {
    int2 E[8];
#pragma unroll
    for (int j = 0; j < 8; ++j) E[j] = edges[e + j];
    uint_t q[8];
#pragma unroll
    for (int j = 0; j < 8; ++j)
      q[j] = *(const uint_t*)(pb + ((((uint_t)E[j].x) >> 1) | fo));
#pragma unroll
    for (int j = 0; j < 8; ++j) {
      float v = __int_as_float(E[j].y);
      a0 = fmaf(v, bf2f(q[j] & 0xFFFFu), a0);
      a1 = fmaf(v, bf2f(q[j] >> 16), a1);
    }
  }
  for (; e < send; ++e) {
    int2 E = edges[e];
    uint_t q = *(const uint_t*)(pb + ((((uint_t)E.x) >> 1) | fo));
    float v = __int_as_float(E.y);
    a0 = fmaf(v, bf2f(q & 0xFFFFu), a0);
    a1 = fmaf(v, bf2f(q >> 16), a1);
  }
  a0 += __shfl_xor(a0, 32);
  a1 += __shfl_xor(a1, 32);
  if (half == 0) {
    uint_t pp = *(const uint_t*)(p1 + (size_t)r * 64 + 2 * f);
    float b0 = a0 + bf2f(pp & 0xFFFFu);
    float b1 = a1 + bf2f(pp >> 16);
    uint_t o = ((uint_t)f2bf(b1) << 16) | (uint_t)f2bf(b0);
    *(uint_t*)(u + (size_t)r * 64 + 2 * f) = o;
  }
}

// ---------------- SpMM, 64 features over idx rows: out = p0[idx] + L u ----------------

__global__ __launch_bounds__(256) void k_spmm64_idx(
    const int* __restrict__ rowptr, const int2* __restrict__ edges,
    const ushort_t* __restrict__ u, const float* __restrict__ p0,
    const int* __restrict__ idx, float* __restrict__ out) {
  int o = blockIdx.x * 4 + (threadIdx.x >> 6);
  int r = idx[o];
  int lane = threadIdx.x & 63;
  int half = lane >> 5, f = lane & 31;
  uint_t fo = (uint_t)f << 2;
  const char* ub = (const char*)u;
  int e0 = rowptr[r], e1 = rowptr[r + 1];
  int ne = e1 - e0;
  int hs = (ne + 1) >> 1;
  int e = e0 + half * hs;
  int send = half ? e1 : (e0 + hs);
  float a0 = 0.f, a1 = 0.f;
  for (; e + 8 <= send; e += 8) {
    int2 E[8];
#pragma unroll
    for (int j = 0; j < 8; ++j) E[j] = edges[e + j];
    uint_t q[8];
#pragma unroll
    for (int j = 0; j < 8; ++j)
      q[j] = *(const uint_t*)(ub + ((((uint_t)E[j].x) >> 1) | fo));
#pragma unroll
    for (int j = 0; j < 8; ++j) {
      float v = __int_as_float(E[j].y);
      a0 = fmaf(v, bf2f(q[j] & 0xFFFFu), a0);
      a1 = fmaf(v, bf2f(q[j] >> 16), a1);
    }
  }
  for (; e < send; ++e) {
    int2 E = edges[e];
    uint_t q = *(const uint_t*)(ub + ((((uint_t)E.x) >> 1) | fo));
    float v = __int_as_float(E.y);
    a0 = fmaf(v, bf2f(q & 0xFFFFu), a0);
    a1 = fmaf(v, bf2f(q >> 16), a1);
  }
  a0 += __shfl_xor(a0, 32);
  a1 += __shfl_xor(a1, 32);
  if (half == 0) {
    float2 b = *(const float2*)(p0 + (size_t)r * 64 + 2 * f);
    float2 w; w.x = b.x + a0; w.y = b.y + a1;
    *(float2*)(out + (size_t)o * 64 + 2 * f) = w;
  }
}

// ---------------- GEMM1: h = relu([x|T1|U] @ Weff1 + b1), M=100k K=384 N=256 ----------
// one wave: 16 rows x 8 n-tiles (ng splits N in half) — acc[8]=32 AGPRs keeps
// occupancy high; round-7's acc[16] variant collapsed occupancy to 35% (119us).

__global__ __launch_bounds__(256) void k_gemm1(
    const ushort_t* __restrict__ A0, const ushort_t* __restrict__ A1,
    const ushort_t* __restrict__ A2, const ushort_t* __restrict__ Bp,
    const float* __restrict__ bias, ushort_t* __restrict__ h) {
  int wid = (blockIdx.x * 256 + threadIdx.x) >> 6;   // 0..12499
  int lane = threadIdx.x & 63;
  int mt = wid >> 1, ng = wid & 1;
  int mr = mt * 16 + (lane & 15);
  int ko = (lane >> 4) << 3;
  floatx4 acc[8] = {};
#pragma unroll
  for (int c = 0; c < 3; ++c) {
    const ushort_t* Ab = (c == 0 ? A0 : c == 1 ? A1 : A2) + (size_t)mr * 128 + ko;
#pragma unroll
    for (int kb = 0; kb < 4; ++kb) {
      bf16x8 a = *(const bf16x8*)(Ab + kb * 32);
      int kbg = c * 4 + kb;
      const ushort_t* Bb = Bp + (((size_t)(kbg * 16 + ng * 8)) * 64 + lane) * 8;
#pragma unroll
      for (int nt = 0; nt < 8; ++nt) {
        bf16x8 b = *(const bf16x8*)(Bb + (size_t)nt * 64 * 8);
        acc[nt] = __builtin_amdgcn_mfma_f32_16x16x32_bf16(a, b, acc[nt], 0, 0, 0);
      }
    }
  }
  int col0 = ng * 128 + (lane & 15);
  int r0 = mt * 16 + ((lane >> 4) << 2);
#pragma unroll
  for (int nt = 0; nt < 8; ++nt) {
    int col = col0 + nt * 16;
    float bv = bias[col];
#pragma unroll
    for (int rg = 0; rg < 4; ++rg) {
      float v = acc[nt][rg] + bv;
      v = v > 0.f ? v : 0.f;
      h[(size_t)(r0 + rg) * 256 + col] = f2bf(v);
    }
  }
}

// ---------------- GEMM2: [p0|p1|p2] = h @ Weff2 (+b2 on p0), M=100k K=256 N=192 -------

__global__ __launch_bounds__(256) void k_gemm2(
    const ushort_t* __restrict__ A, const ushort_t* __restrict__ Bp,
    const float* __restrict__ bias, float* __restrict__ p0,
    ushort_t* __restrict__ p1, ushort_t* __restrict__ p2) {
  int wid = (blockIdx.x * 256 + threadIdx.x) >> 6;
  if (wid >= 18750) return;
  int lane = threadIdx.x & 63;
  int mt = wid / 3, ng = wid - mt * 3;   // ng: 0=p0, 1=p1, 2=p2
  int mr = mt * 16 + (lane & 15);
  int ko = (lane >> 4) << 3;
  floatx4 acc[4] = {};
  const ushort_t* Ab = A + (size_t)mr * 256 + ko;
#pragma unroll
  for (int kb = 0; kb < 8; ++kb) {
    bf16x8 a = *(const bf16x8*)(Ab + kb * 32);
    const ushort_t* Bb = Bp + (((size_t)(kb * 12 + ng * 4)) * 64 + lane) * 8;
#pragma unroll
    for (int nt = 0; nt < 4; ++nt) {
      bf16x8 b = *(const bf16x8*)(Bb + (size_t)nt * 64 * 8);
      acc[nt] = __builtin_amdgcn_mfma_f32_16x16x32_bf16(a, b, acc[nt], 0, 0, 0);
    }
  }
  int c16 = lane & 15;
  int r0 = mt * 16 + ((lane >> 4) << 2);
  if (ng == 0) {
#pragma unroll
    for (int nt = 0; nt < 4; ++nt) {
      float bv = bias[nt * 16 + c16];
#pragma unroll
      for (int rg = 0; rg < 4; ++rg)
        p0[(size_t)(r0 + rg) * 64 + nt * 16 + c16] = acc[nt][rg] + bv;
    }
  } else {
    ushort_t* dst = (ng == 1) ? p1 : p2;
#pragma unroll
    for (int nt = 0; nt < 4; ++nt)
#pragma unroll
      for (int rg = 0; rg < 4; ++rg)
        dst[(size_t)(r0 + rg) * 64 + nt * 16 + c16] = f2bf(acc[nt][rg]);
  }
}

// ---------------- launch ----------------

extern "C" void kernel_launch(void* const* d_in, const int* in_sizes, int n_in,
                              void* d_out, int out_size, void* d_ws, size_t ws_size,
                              hipStream_t stream) {
  const float* x    = (const float*)d_in[0];
  const float* vals = (const float*)d_in[1];
  const float* W1   = (const float*)d_in[2];
  const float* b1   = (const float*)d_in[3];
  const float* W2   = (const float*)d_in[4];
  const float* b2   = (const float*)d_in[5];
  const int*   rows = (const int*)d_in[6];
  const int*   cols = (const int*)d_in[7];
  const int*   idx  = (const int*)d_in[8];
  float* out = (float*)d_out;

  char* w = (char*)d_ws;
  size_t off = 0;
  auto take = [&](size_t b) -> char* {
    char* p = w + off;
    off += (b + 255) & ~(size_t)255;
    return p;
  };
  int*      bcnt    = (int*)take((size_t)NB_BKT * 4);
  int*      bbase   = (int*)take((size_t)NB_BKT * 4);
  int*      bcur    = (int*)take((size_t)NB_BKT * 4);
  int*      rowptr  = (int*)take((size_t)(N_NODES + 1) * 4);
  int2*     tmp     = (int2*)take((size_t)NNZ_E * 8);
  int2*     edges   = (int2*)take((size_t)NNZ_E * 8);
  ushort_t* xb      = (ushort_t*)take((size_t)N_NODES * 128 * 2);  // later: p0 (fp32 100k x 64)
  ushort_t* T1a     = (ushort_t*)take((size_t)N_NODES * 128 * 2);  // later: p1 | p2
  ushort_t* U1      = (ushort_t*)take((size_t)N_NODES * 128 * 2);  // later: u
  ushort_t* h       = (ushort_t*)take((size_t)N_NODES * 256 * 2);
  ushort_t* W1p     = (ushort_t*)take((size_t)384 * 256 * 2);
  ushort_t* W2p     = (ushort_t*)take((size_t)256 * 192 * 2);

  // overlays (dead after GEMM1 consumes xb/T1a/U1)
  float*    p0 = (float*)xb;                                   // 25.6 MB, exact fit
  ushort_t* p1 = T1a;                                          // 12.8 MB
  ushort_t* p2 = T1a + (size_t)N_NODES * 64;                   // 12.8 MB
  ushort_t* u  = U1;                                           // 12.8 MB

  // CSR build (graph shared by both layers)
  hipMemsetAsync(bcnt, 0, (size_t)NB_BKT * 4, stream);
  k_bhist<<<PBLOCKS, 256, 0, stream>>>(rows, bcnt);
  k_bscan<<<1, 256, 0, stream>>>(bcnt, bbase, bcur);
  k_part<<<PBLOCKS, 256, 0, stream>>>(rows, cols, vals, bcur, tmp);
  k_sort<<<NB_BKT, 512, 0, stream>>>(bbase, tmp, edges, rowptr);

  // prep
  k_cvt<<<(N_NODES * 128 / 4 + 255) / 256, 256, 0, stream>>>((const float4*)x, (ushort4*)xb);
  k_prepW1<<<384, 256, 0, stream>>>(W1, W1p);
  k_prepW2<<<256, 192, 0, stream>>>(W2, W2p);

  // layer 1: T1 = L x ; U = L T1 ; h = relu([x|T1|U] @ Weff1 + b1)
  k_spmm128<<<N_NODES / 4, 256, 0, stream>>>(rowptr, edges, xb, T1a);
  k_spmm128<<<N_NODES / 4, 256, 0, stream>>>(rowptr, edges, T1a, U1);
  k_gemm1<<<3125, 256, 0, stream>>>(xb, T1a, U1, W1p, b1, h);

  // layer 2 (L pushed past the GEMM): [p0|p1|p2] = h @ Weff2 ; u = p1 + L p2 ;
  // out = p0[idx] + (L u)[idx]
  k_gemm2<<<4688, 256, 0, stream>>>(h, W2p, b2, p0, p1, p2);
  k_spmm64_add<<<N_NODES / 4, 256, 0, stream>>>(rowptr, edges, p2, p1, u);
  k_spmm64_idx<<<N_IDX / 4, 256, 0, stream>>>(rowptr, edges, u, p0, idx, out);
}